// Round 1
// baseline (3220.679 us; speedup 1.0000x reference)
//
#include <hip/hip_runtime.h>

#define N_D 128
#define N_H 256
#define EPSV 1e-5f
#define TM 64
#define TN 64
#define BK 16
#define STAT_ROWS 256

// ---------------- SpMM: agg[row] += val * input[col] ----------------
// 32 threads per edge, float4 per thread (128 floats / edge).
__global__ __launch_bounds__(256) void spmm_kernel(
    const float* __restrict__ input,
    const int* __restrict__ rows,
    const int* __restrict__ cols,
    const float* __restrict__ vals,
    float* __restrict__ agg,
    int E)
{
    int gid = blockIdx.x * 256 + threadIdx.x;
    int e = gid >> 5;
    if (e >= E) return;
    int c = (gid & 31) << 2;
    int r = rows[e];
    int cl = cols[e];
    float v = vals[e];
    const float4 x = *(const float4*)(input + (size_t)cl * N_D + c);
    float* dst = agg + (size_t)r * N_D + c;
    atomicAdd(dst + 0, v * x.x);
    atomicAdd(dst + 1, v * x.y);
    atomicAdd(dst + 2, v * x.z);
    atomicAdd(dst + 3, v * x.w);
}

// ------------- column sums / sumsq of concat([input, agg]) -------------
// thread t<128 -> input col t ; t>=128 -> agg col t-128. Coalesced row-major.
__global__ __launch_bounds__(256) void colstats_kernel(
    const float* __restrict__ input, const float* __restrict__ agg,
    float* __restrict__ sums, float* __restrict__ sumsq, int n)
{
    int t = threadIdx.x;
    const float* base = (t < N_D) ? input : agg;
    int col = t & (N_D - 1);
    int r0 = blockIdx.x * STAT_ROWS;
    int r1 = min(n, r0 + STAT_ROWS);
    float s = 0.f, q = 0.f;
    for (int r = r0; r < r1; ++r) {
        float x = base[(size_t)r * N_D + col];
        s += x; q += x * x;
    }
    atomicAdd(&sums[t], s);
    atomicAdd(&sumsq[t], q);
}

// ------------- fold BN1 into GEMM1: a1 = rs*gamma1 ; b1' = c1 @ W1 + b1 -------------
__global__ __launch_bounds__(256) void prep1_kernel(
    const float* __restrict__ sums, const float* __restrict__ sumsq,
    const float* __restrict__ gamma1, const float* __restrict__ beta1,
    const float* __restrict__ W1, const float* __restrict__ b1,
    float* __restrict__ a1, float* __restrict__ b1p, float n)
{
    __shared__ float c1s[N_H];
    int t = threadIdx.x;
    float mu = sums[t] / n;
    float var = sumsq[t] / n - mu * mu;
    float rs = rsqrtf(var + EPSV);
    float a = rs * gamma1[t];
    a1[t] = a;
    c1s[t] = beta1[t] - mu * a;
    __syncthreads();
    float acc = b1[t];
    for (int k = 0; k < N_H; ++k)
        acc += c1s[k] * W1[(size_t)k * N_H + t];
    b1p[t] = acc;
}

// ------------- BN2 per-column affine from accumulated stats -------------
__global__ __launch_bounds__(256) void prep2_kernel(
    const float* __restrict__ sums2, const float* __restrict__ sumsq2,
    const float* __restrict__ gamma2, const float* __restrict__ beta2,
    float* __restrict__ a2, float* __restrict__ c2, float n)
{
    int t = threadIdx.x;
    float mu = sums2[t] / n;
    float var = sumsq2[t] / n - mu * mu;
    float rs = rsqrtf(var + EPSV);
    float a = rs * gamma2[t];
    a2[t] = a;
    c2[t] = beta2[t] - mu * a;
}

// ------------- GEMM1: y = xcat @ (diag(a1) W1) + b1'  + column stats of y -------------
__global__ __launch_bounds__(256) void gemm1_kernel(
    const float* __restrict__ input, const float* __restrict__ agg,
    const float* __restrict__ W1, const float* __restrict__ a1,
    const float* __restrict__ b1p, float* __restrict__ y,
    float* __restrict__ sums2, float* __restrict__ sumsq2, int n)
{
    __shared__ __align__(16) float As[BK][TM];
    __shared__ __align__(16) float Bs[BK][TN];
    __shared__ float ssum[TN];
    __shared__ float ssq[TN];
    int t = threadIdx.x;
    int tx = t & 15, ty = t >> 4;
    int row0 = blockIdx.x * TM;
    int col0 = blockIdx.y * TN;
    int lr = t >> 2;     // A-load row 0..63
    int lq = t & 3;      // A-load quad in k
    int bkk = t >> 4;    // B-load k row 0..15
    int bq = t & 15;     // B-load col quad
    float acc[4][4] = {{0.f}};
    for (int k0 = 0; k0 < N_H; k0 += BK) {
        const float* Abase = (k0 < N_D) ? input : agg;   // concat halves
        int kloc = (k0 & (N_D - 1)) + lq * 4;
        int r = row0 + lr;
        float4 av = make_float4(0.f, 0.f, 0.f, 0.f);
        if (r < n) av = *(const float4*)(Abase + (size_t)r * N_D + kloc);
        As[lq * 4 + 0][lr] = av.x;
        As[lq * 4 + 1][lr] = av.y;
        As[lq * 4 + 2][lr] = av.z;
        As[lq * 4 + 3][lr] = av.w;
        float sc = a1[k0 + bkk];                          // fold BN1 scale into B
        float4 bv = *(const float4*)(W1 + (size_t)(k0 + bkk) * N_H + col0 + bq * 4);
        Bs[bkk][bq * 4 + 0] = sc * bv.x;
        Bs[bkk][bq * 4 + 1] = sc * bv.y;
        Bs[bkk][bq * 4 + 2] = sc * bv.z;
        Bs[bkk][bq * 4 + 3] = sc * bv.w;
        __syncthreads();
#pragma unroll
        for (int kk = 0; kk < BK; ++kk) {
            float4 a = *(const float4*)&As[kk][ty * 4];
            float4 b = *(const float4*)&Bs[kk][tx * 4];
            acc[0][0] += a.x * b.x; acc[0][1] += a.x * b.y; acc[0][2] += a.x * b.z; acc[0][3] += a.x * b.w;
            acc[1][0] += a.y * b.x; acc[1][1] += a.y * b.y; acc[1][2] += a.y * b.z; acc[1][3] += a.y * b.w;
            acc[2][0] += a.z * b.x; acc[2][1] += a.z * b.y; acc[2][2] += a.z * b.z; acc[2][3] += a.z * b.w;
            acc[3][0] += a.w * b.x; acc[3][1] += a.w * b.y; acc[3][2] += a.w * b.z; acc[3][3] += a.w * b.w;
        }
        __syncthreads();
    }
    if (t < TN) { ssum[t] = 0.f; ssq[t] = 0.f; }
    __syncthreads();
    float4 bb = *(const float4*)(b1p + col0 + tx * 4);
    float cs[4] = {0.f, 0.f, 0.f, 0.f};
    float cq[4] = {0.f, 0.f, 0.f, 0.f};
#pragma unroll
    for (int i = 0; i < 4; ++i) {
        int r = row0 + ty * 4 + i;
        if (r < n) {
            float4 v;
            v.x = acc[i][0] + bb.x;
            v.y = acc[i][1] + bb.y;
            v.z = acc[i][2] + bb.z;
            v.w = acc[i][3] + bb.w;
            *(float4*)(y + (size_t)r * N_H + col0 + tx * 4) = v;
            cs[0] += v.x; cq[0] += v.x * v.x;
            cs[1] += v.y; cq[1] += v.y * v.y;
            cs[2] += v.z; cq[2] += v.z * v.z;
            cs[3] += v.w; cq[3] += v.w * v.w;
        }
    }
#pragma unroll
    for (int j = 0; j < 4; ++j) {
        atomicAdd(&ssum[tx * 4 + j], cs[j]);
        atomicAdd(&ssq[tx * 4 + j], cq[j]);
    }
    __syncthreads();
    if (t < TN) {
        atomicAdd(&sums2[col0 + t], ssum[t]);
        atomicAdd(&sumsq2[col0 + t], ssq[t]);
    }
}

// ------------- GEMM2: out = relu(y*a2 + c2) @ W2 + b2 -------------
__global__ __launch_bounds__(256) void gemm2_kernel(
    const float* __restrict__ y, const float* __restrict__ W2,
    const float* __restrict__ a2, const float* __restrict__ c2,
    const float* __restrict__ b2, float* __restrict__ out, int n)
{
    __shared__ __align__(16) float As[BK][TM];
    __shared__ __align__(16) float Bs[BK][TN];
    int t = threadIdx.x;
    int tx = t & 15, ty = t >> 4;
    int row0 = blockIdx.x * TM;
    int col0 = blockIdx.y * TN;
    int lr = t >> 2;
    int lq = t & 3;
    int bkk = t >> 4;
    int bq = t & 15;
    float acc[4][4] = {{0.f}};
    for (int k0 = 0; k0 < N_H; k0 += BK) {
        int kk0 = k0 + lq * 4;
        int r = row0 + lr;
        float4 av = make_float4(0.f, 0.f, 0.f, 0.f);
        if (r < n) av = *(const float4*)(y + (size_t)r * N_H + kk0);
        float4 aa = *(const float4*)(a2 + kk0);
        float4 cc = *(const float4*)(c2 + kk0);
        As[lq * 4 + 0][lr] = fmaxf(av.x * aa.x + cc.x, 0.f);
        As[lq * 4 + 1][lr] = fmaxf(av.y * aa.y + cc.y, 0.f);
        As[lq * 4 + 2][lr] = fmaxf(av.z * aa.z + cc.z, 0.f);
        As[lq * 4 + 3][lr] = fmaxf(av.w * aa.w + cc.w, 0.f);
        float4 bv = *(const float4*)(W2 + (size_t)(k0 + bkk) * N_D + col0 + bq * 4);
        Bs[bkk][bq * 4 + 0] = bv.x;
        Bs[bkk][bq * 4 + 1] = bv.y;
        Bs[bkk][bq * 4 + 2] = bv.z;
        Bs[bkk][bq * 4 + 3] = bv.w;
        __syncthreads();
#pragma unroll
        for (int kk = 0; kk < BK; ++kk) {
            float4 a = *(const float4*)&As[kk][ty * 4];
            float4 b = *(const float4*)&Bs[kk][tx * 4];
            acc[0][0] += a.x * b.x; acc[0][1] += a.x * b.y; acc[0][2] += a.x * b.z; acc[0][3] += a.x * b.w;
            acc[1][0] += a.y * b.x; acc[1][1] += a.y * b.y; acc[1][2] += a.y * b.z; acc[1][3] += a.y * b.w;
            acc[2][0] += a.z * b.x; acc[2][1] += a.z * b.y; acc[2][2] += a.z * b.z; acc[2][3] += a.z * b.w;
            acc[3][0] += a.w * b.x; acc[3][1] += a.w * b.y; acc[3][2] += a.w * b.z; acc[3][3] += a.w * b.w;
        }
        __syncthreads();
    }
    float4 bb = *(const float4*)(b2 + col0 + tx * 4);
#pragma unroll
    for (int i = 0; i < 4; ++i) {
        int r = row0 + ty * 4 + i;
        if (r < n) {
            float4 v;
            v.x = acc[i][0] + bb.x;
            v.y = acc[i][1] + bb.y;
            v.z = acc[i][2] + bb.z;
            v.w = acc[i][3] + bb.w;
            *(float4*)(out + (size_t)r * N_D + col0 + tx * 4) = v;
        }
    }
}

extern "C" void kernel_launch(void* const* d_in, const int* in_sizes, int n_in,
                              void* d_out, int out_size, void* d_ws, size_t ws_size,
                              hipStream_t stream)
{
    const float* input    = (const float*)d_in[0];
    const int*   adj_rows = (const int*)d_in[1];
    const int*   adj_cols = (const int*)d_in[2];
    const float* adj_vals = (const float*)d_in[3];
    const float* gamma1   = (const float*)d_in[4];
    const float* beta1    = (const float*)d_in[5];
    const float* W1       = (const float*)d_in[6];
    const float* b1       = (const float*)d_in[7];
    const float* gamma2   = (const float*)d_in[8];
    const float* beta2    = (const float*)d_in[9];
    const float* W2       = (const float*)d_in[10];
    const float* b2       = (const float*)d_in[11];

    int n = in_sizes[0] / N_D;   // 100000
    int E = in_sizes[1];         // 1600000

    float* ws     = (float*)d_ws;
    float* agg    = ws;                                // n*128 floats
    float* y      = agg + (size_t)n * N_D;             // n*256 floats
    float* stats  = y + (size_t)n * N_H;               // 2048 floats
    float* sums1  = stats;
    float* sumsq1 = stats + 256;
    float* a1     = stats + 512;
    float* b1p    = stats + 768;
    float* sums2  = stats + 1024;
    float* sumsq2 = stats + 1280;
    float* a2     = stats + 1536;
    float* c2     = stats + 1792;

    // ws is poisoned 0xAA before every timed launch: zero the accumulators.
    hipMemsetAsync(agg, 0, (size_t)n * N_D * sizeof(float), stream);
    hipMemsetAsync(stats, 0, 2048 * sizeof(float), stream);

    int spmm_blocks = (E * 32 + 255) / 256;
    spmm_kernel<<<spmm_blocks, 256, 0, stream>>>(input, adj_rows, adj_cols, adj_vals, agg, E);

    int stat_blocks = (n + STAT_ROWS - 1) / STAT_ROWS;
    colstats_kernel<<<stat_blocks, 256, 0, stream>>>(input, agg, sums1, sumsq1, n);

    prep1_kernel<<<1, 256, 0, stream>>>(sums1, sumsq1, gamma1, beta1, W1, b1, a1, b1p, (float)n);

    dim3 g1((n + TM - 1) / TM, N_H / TN);
    gemm1_kernel<<<g1, 256, 0, stream>>>(input, agg, W1, a1, b1p, y, sums2, sumsq2, n);

    prep2_kernel<<<1, 256, 0, stream>>>(sums2, sumsq2, gamma2, beta2, a2, c2, (float)n);

    dim3 g2((n + TM - 1) / TM, N_D / TN);
    gemm2_kernel<<<g2, 256, 0, stream>>>(y, W2, a2, c2, b2, (float*)d_out, n);
}

// Round 2
// 884.084 us; speedup vs baseline: 3.6430x; 3.6430x over previous
//
#include <hip/hip_runtime.h>

#define N_D 128
#define N_H 256
#define EPSV 1e-5f
#define TM 64
#define TN 64
#define BK 16
#define STAT_ROWS 256
#define SCAN_B 1024

// ---------------- Stage 1: count edges per row ----------------
__global__ __launch_bounds__(256) void count_kernel(
    const int* __restrict__ rows, int* __restrict__ cnt, int E)
{
    int e = blockIdx.x * 256 + threadIdx.x;
    if (e < E) atomicAdd(&cnt[rows[e]], 1);
}

// ---------------- Stage 2: exclusive scan (3 kernels) ----------------
__global__ __launch_bounds__(SCAN_B) void scanA_kernel(
    const int* __restrict__ cnt, int* __restrict__ rowPtr,
    int* __restrict__ blockSums, int n)
{
    __shared__ int sm[SCAN_B];
    int t = threadIdx.x;
    int i = blockIdx.x * SCAN_B + t;
    int v = (i < n) ? cnt[i] : 0;
    sm[t] = v;
    __syncthreads();
    for (int off = 1; off < SCAN_B; off <<= 1) {
        int x = (t >= off) ? sm[t - off] : 0;
        __syncthreads();
        sm[t] += x;
        __syncthreads();
    }
    if (i < n) rowPtr[i] = sm[t] - v;              // exclusive
    if (t == SCAN_B - 1) blockSums[blockIdx.x] = sm[t];
}

__global__ __launch_bounds__(128) void scanB_kernel(int* __restrict__ blockSums, int nb)
{
    __shared__ int sm[128];
    int t = threadIdx.x;
    int v = (t < nb) ? blockSums[t] : 0;
    sm[t] = v;
    __syncthreads();
    for (int off = 1; off < 128; off <<= 1) {
        int x = (t >= off) ? sm[t - off] : 0;
        __syncthreads();
        sm[t] += x;
        __syncthreads();
    }
    if (t < nb) blockSums[t] = sm[t] - v;          // exclusive block offsets
}

__global__ __launch_bounds__(SCAN_B) void scanC_kernel(
    int* __restrict__ rowPtr, const int* __restrict__ blockSums, int n)
{
    int i = blockIdx.x * SCAN_B + threadIdx.x;
    if (i < n) rowPtr[i] += blockSums[blockIdx.x];
}

// ---------------- Stage 3: scatter edges into CSR order ----------------
// rowPtr is mutated into END pointers (start = end - cnt).
__global__ __launch_bounds__(256) void scatter_kernel(
    const int* __restrict__ rows, const int* __restrict__ cols,
    const float* __restrict__ vals, int* __restrict__ rowPtr,
    int* __restrict__ ecol, float* __restrict__ eval, int E)
{
    int e = blockIdx.x * 256 + threadIdx.x;
    if (e >= E) return;
    int r = rows[e];
    int pos = atomicAdd(&rowPtr[r], 1);
    ecol[pos] = cols[e];
    eval[pos] = vals[e];
}

// ---------------- Stage 4: gather-reduce, one wave per row ----------------
// lane l owns feature float2 [2l,2l+1]; 512B coalesced gather per edge.
__global__ __launch_bounds__(256) void aggregate_kernel(
    const float* __restrict__ input,
    const int* __restrict__ rowPtrEnd, const int* __restrict__ cnt,
    const int* __restrict__ ecol, const float* __restrict__ eval,
    float* __restrict__ agg, int n)
{
    int wave = (blockIdx.x * 256 + threadIdx.x) >> 6;
    if (wave >= n) return;
    int lane = threadIdx.x & 63;
    int end = rowPtrEnd[wave];
    int start = end - cnt[wave];
    const float2* inp2 = (const float2*)input;
    float2 acc = make_float2(0.f, 0.f);
    for (int e = start; e < end; ++e) {
        int c = ecol[e];            // wave-uniform -> broadcast
        float v = eval[e];
        float2 x = inp2[(size_t)c * 64 + lane];
        acc.x += v * x.x;
        acc.y += v * x.y;
    }
    ((float2*)agg)[(size_t)wave * 64 + lane] = acc;
}

// ------------- column sums / sumsq of concat([input, agg]) -------------
__global__ __launch_bounds__(256) void colstats_kernel(
    const float* __restrict__ input, const float* __restrict__ agg,
    float* __restrict__ sums, float* __restrict__ sumsq, int n)
{
    int t = threadIdx.x;
    const float* base = (t < N_D) ? input : agg;
    int col = t & (N_D - 1);
    int r0 = blockIdx.x * STAT_ROWS;
    int r1 = min(n, r0 + STAT_ROWS);
    float s = 0.f, q = 0.f;
    for (int r = r0; r < r1; ++r) {
        float x = base[(size_t)r * N_D + col];
        s += x; q += x * x;
    }
    atomicAdd(&sums[t], s);
    atomicAdd(&sumsq[t], q);
}

// ------------- fold BN1 into GEMM1: a1 = rs*gamma1 ; b1' = c1 @ W1 + b1 -------------
__global__ __launch_bounds__(256) void prep1_kernel(
    const float* __restrict__ sums, const float* __restrict__ sumsq,
    const float* __restrict__ gamma1, const float* __restrict__ beta1,
    const float* __restrict__ W1, const float* __restrict__ b1,
    float* __restrict__ a1, float* __restrict__ b1p, float n)
{
    __shared__ float c1s[N_H];
    int t = threadIdx.x;
    float mu = sums[t] / n;
    float var = sumsq[t] / n - mu * mu;
    float rs = rsqrtf(var + EPSV);
    float a = rs * gamma1[t];
    a1[t] = a;
    c1s[t] = beta1[t] - mu * a;
    __syncthreads();
    float acc = b1[t];
    for (int k = 0; k < N_H; ++k)
        acc += c1s[k] * W1[(size_t)k * N_H + t];
    b1p[t] = acc;
}

// ------------- BN2 per-column affine from accumulated stats -------------
__global__ __launch_bounds__(256) void prep2_kernel(
    const float* __restrict__ sums2, const float* __restrict__ sumsq2,
    const float* __restrict__ gamma2, const float* __restrict__ beta2,
    float* __restrict__ a2, float* __restrict__ c2, float n)
{
    int t = threadIdx.x;
    float mu = sums2[t] / n;
    float var = sumsq2[t] / n - mu * mu;
    float rs = rsqrtf(var + EPSV);
    float a = rs * gamma2[t];
    a2[t] = a;
    c2[t] = beta2[t] - mu * a;
}

// ------------- GEMM1: y = xcat @ (diag(a1) W1) + b1'  + column stats of y -------------
__global__ __launch_bounds__(256) void gemm1_kernel(
    const float* __restrict__ input, const float* __restrict__ agg,
    const float* __restrict__ W1, const float* __restrict__ a1,
    const float* __restrict__ b1p, float* __restrict__ y,
    float* __restrict__ sums2, float* __restrict__ sumsq2, int n)
{
    __shared__ __align__(16) float As[BK][TM];
    __shared__ __align__(16) float Bs[BK][TN];
    __shared__ float ssum[TN];
    __shared__ float ssq[TN];
    int t = threadIdx.x;
    int tx = t & 15, ty = t >> 4;
    int row0 = blockIdx.x * TM;
    int col0 = blockIdx.y * TN;
    int lr = t >> 2;
    int lq = t & 3;
    int bkk = t >> 4;
    int bq = t & 15;
    float acc[4][4] = {{0.f}};
    for (int k0 = 0; k0 < N_H; k0 += BK) {
        const float* Abase = (k0 < N_D) ? input : agg;
        int kloc = (k0 & (N_D - 1)) + lq * 4;
        int r = row0 + lr;
        float4 av = make_float4(0.f, 0.f, 0.f, 0.f);
        if (r < n) av = *(const float4*)(Abase + (size_t)r * N_D + kloc);
        As[lq * 4 + 0][lr] = av.x;
        As[lq * 4 + 1][lr] = av.y;
        As[lq * 4 + 2][lr] = av.z;
        As[lq * 4 + 3][lr] = av.w;
        float sc = a1[k0 + bkk];
        float4 bv = *(const float4*)(W1 + (size_t)(k0 + bkk) * N_H + col0 + bq * 4);
        Bs[bkk][bq * 4 + 0] = sc * bv.x;
        Bs[bkk][bq * 4 + 1] = sc * bv.y;
        Bs[bkk][bq * 4 + 2] = sc * bv.z;
        Bs[bkk][bq * 4 + 3] = sc * bv.w;
        __syncthreads();
#pragma unroll
        for (int kk = 0; kk < BK; ++kk) {
            float4 a = *(const float4*)&As[kk][ty * 4];
            float4 b = *(const float4*)&Bs[kk][tx * 4];
            acc[0][0] += a.x * b.x; acc[0][1] += a.x * b.y; acc[0][2] += a.x * b.z; acc[0][3] += a.x * b.w;
            acc[1][0] += a.y * b.x; acc[1][1] += a.y * b.y; acc[1][2] += a.y * b.z; acc[1][3] += a.y * b.w;
            acc[2][0] += a.z * b.x; acc[2][1] += a.z * b.y; acc[2][2] += a.z * b.z; acc[2][3] += a.z * b.w;
            acc[3][0] += a.w * b.x; acc[3][1] += a.w * b.y; acc[3][2] += a.w * b.z; acc[3][3] += a.w * b.w;
        }
        __syncthreads();
    }
    if (t < TN) { ssum[t] = 0.f; ssq[t] = 0.f; }
    __syncthreads();
    float4 bb = *(const float4*)(b1p + col0 + tx * 4);
    float cs[4] = {0.f, 0.f, 0.f, 0.f};
    float cq[4] = {0.f, 0.f, 0.f, 0.f};
#pragma unroll
    for (int i = 0; i < 4; ++i) {
        int r = row0 + ty * 4 + i;
        if (r < n) {
            float4 v;
            v.x = acc[i][0] + bb.x;
            v.y = acc[i][1] + bb.y;
            v.z = acc[i][2] + bb.z;
            v.w = acc[i][3] + bb.w;
            *(float4*)(y + (size_t)r * N_H + col0 + tx * 4) = v;
            cs[0] += v.x; cq[0] += v.x * v.x;
            cs[1] += v.y; cq[1] += v.y * v.y;
            cs[2] += v.z; cq[2] += v.z * v.z;
            cs[3] += v.w; cq[3] += v.w * v.w;
        }
    }
#pragma unroll
    for (int j = 0; j < 4; ++j) {
        atomicAdd(&ssum[tx * 4 + j], cs[j]);
        atomicAdd(&ssq[tx * 4 + j], cq[j]);
    }
    __syncthreads();
    if (t < TN) {
        atomicAdd(&sums2[col0 + t], ssum[t]);
        atomicAdd(&sumsq2[col0 + t], ssq[t]);
    }
}

// ------------- GEMM2: out = relu(y*a2 + c2) @ W2 + b2 -------------
__global__ __launch_bounds__(256) void gemm2_kernel(
    const float* __restrict__ y, const float* __restrict__ W2,
    const float* __restrict__ a2, const float* __restrict__ c2,
    const float* __restrict__ b2, float* __restrict__ out, int n)
{
    __shared__ __align__(16) float As[BK][TM];
    __shared__ __align__(16) float Bs[BK][TN];
    int t = threadIdx.x;
    int tx = t & 15, ty = t >> 4;
    int row0 = blockIdx.x * TM;
    int col0 = blockIdx.y * TN;
    int lr = t >> 2;
    int lq = t & 3;
    int bkk = t >> 4;
    int bq = t & 15;
    float acc[4][4] = {{0.f}};
    for (int k0 = 0; k0 < N_H; k0 += BK) {
        int kk0 = k0 + lq * 4;
        int r = row0 + lr;
        float4 av = make_float4(0.f, 0.f, 0.f, 0.f);
        if (r < n) av = *(const float4*)(y + (size_t)r * N_H + kk0);
        float4 aa = *(const float4*)(a2 + kk0);
        float4 cc = *(const float4*)(c2 + kk0);
        As[lq * 4 + 0][lr] = fmaxf(av.x * aa.x + cc.x, 0.f);
        As[lq * 4 + 1][lr] = fmaxf(av.y * aa.y + cc.y, 0.f);
        As[lq * 4 + 2][lr] = fmaxf(av.z * aa.z + cc.z, 0.f);
        As[lq * 4 + 3][lr] = fmaxf(av.w * aa.w + cc.w, 0.f);
        float4 bv = *(const float4*)(W2 + (size_t)(k0 + bkk) * N_D + col0 + bq * 4);
        Bs[bkk][bq * 4 + 0] = bv.x;
        Bs[bkk][bq * 4 + 1] = bv.y;
        Bs[bkk][bq * 4 + 2] = bv.z;
        Bs[bkk][bq * 4 + 3] = bv.w;
        __syncthreads();
#pragma unroll
        for (int kk = 0; kk < BK; ++kk) {
            float4 a = *(const float4*)&As[kk][ty * 4];
            float4 b = *(const float4*)&Bs[kk][tx * 4];
            acc[0][0] += a.x * b.x; acc[0][1] += a.x * b.y; acc[0][2] += a.x * b.z; acc[0][3] += a.x * b.w;
            acc[1][0] += a.y * b.x; acc[1][1] += a.y * b.y; acc[1][2] += a.y * b.z; acc[1][3] += a.y * b.w;
            acc[2][0] += a.z * b.x; acc[2][1] += a.z * b.y; acc[2][2] += a.z * b.z; acc[2][3] += a.z * b.w;
            acc[3][0] += a.w * b.x; acc[3][1] += a.w * b.y; acc[3][2] += a.w * b.z; acc[3][3] += a.w * b.w;
        }
        __syncthreads();
    }
    float4 bb = *(const float4*)(b2 + col0 + tx * 4);
#pragma unroll
    for (int i = 0; i < 4; ++i) {
        int r = row0 + ty * 4 + i;
        if (r < n) {
            float4 v;
            v.x = acc[i][0] + bb.x;
            v.y = acc[i][1] + bb.y;
            v.z = acc[i][2] + bb.z;
            v.w = acc[i][3] + bb.w;
            *(float4*)(out + (size_t)r * N_D + col0 + tx * 4) = v;
        }
    }
}

extern "C" void kernel_launch(void* const* d_in, const int* in_sizes, int n_in,
                              void* d_out, int out_size, void* d_ws, size_t ws_size,
                              hipStream_t stream)
{
    const float* input    = (const float*)d_in[0];
    const int*   adj_rows = (const int*)d_in[1];
    const int*   adj_cols = (const int*)d_in[2];
    const float* adj_vals = (const float*)d_in[3];
    const float* gamma1   = (const float*)d_in[4];
    const float* beta1    = (const float*)d_in[5];
    const float* W1       = (const float*)d_in[6];
    const float* b1       = (const float*)d_in[7];
    const float* gamma2   = (const float*)d_in[8];
    const float* beta2    = (const float*)d_in[9];
    const float* W2       = (const float*)d_in[10];
    const float* b2       = (const float*)d_in[11];

    int n = in_sizes[0] / N_D;   // 100000
    int E = in_sizes[1];         // 1600000

    float* ws     = (float*)d_ws;
    float* agg    = ws;                                // n*128 floats
    float* y      = agg + (size_t)n * N_D;             // n*256 floats
    // CSR edge arrays alias y: consumed by aggregate_kernel BEFORE gemm1 writes y.
    int*   ecol   = (int*)y;                           // E ints
    float* eval_  = y + E;                             // E floats
    float* stats  = y + (size_t)n * N_H;               // 2048 floats
    float* sums1  = stats;
    float* sumsq1 = stats + 256;
    float* a1     = stats + 512;
    float* b1p    = stats + 768;
    float* sums2  = stats + 1024;
    float* sumsq2 = stats + 1280;
    float* a2     = stats + 1536;
    float* c2     = stats + 1792;
    int*   cnt    = (int*)(stats + 2048);              // n ints
    int*   rowPtr = cnt + n;                           // n ints
    int*   blockSums = rowPtr + n;                     // 128 ints

    hipMemsetAsync(cnt, 0, (size_t)n * sizeof(int), stream);
    hipMemsetAsync(stats, 0, 2048 * sizeof(float), stream);

    int eb = (E + 255) / 256;
    count_kernel<<<eb, 256, 0, stream>>>(adj_rows, cnt, E);

    int nb = (n + SCAN_B - 1) / SCAN_B;                // 98 <= 128
    scanA_kernel<<<nb, SCAN_B, 0, stream>>>(cnt, rowPtr, blockSums, n);
    scanB_kernel<<<1, 128, 0, stream>>>(blockSums, nb);
    scanC_kernel<<<nb, SCAN_B, 0, stream>>>(rowPtr, blockSums, n);

    scatter_kernel<<<eb, 256, 0, stream>>>(adj_rows, adj_cols, adj_vals, rowPtr, ecol, eval_, E);

    aggregate_kernel<<<(n + 3) / 4, 256, 0, stream>>>(input, rowPtr, cnt, ecol, eval_, agg, n);

    int stat_blocks = (n + STAT_ROWS - 1) / STAT_ROWS;
    colstats_kernel<<<stat_blocks, 256, 0, stream>>>(input, agg, sums1, sumsq1, n);

    prep1_kernel<<<1, 256, 0, stream>>>(sums1, sumsq1, gamma1, beta1, W1, b1, a1, b1p, (float)n);

    dim3 g1((n + TM - 1) / TM, N_H / TN);
    gemm1_kernel<<<g1, 256, 0, stream>>>(input, agg, W1, a1, b1p, y, sums2, sumsq2, n);

    prep2_kernel<<<1, 256, 0, stream>>>(sums2, sumsq2, gamma2, beta2, a2, c2, (float)n);

    dim3 g2((n + TM - 1) / TM, N_D / TN);
    gemm2_kernel<<<g2, 256, 0, stream>>>(y, W2, a2, c2, b2, (float*)d_out, n);
}

// Round 3
// 681.175 us; speedup vs baseline: 4.7281x; 1.2979x over previous
//
#include <hip/hip_runtime.h>

#define N_D 128
#define N_H 256
#define EPSV 1e-5f
#define STAT_ROWS 256
#define SCAN_B 1024

typedef unsigned short u16;
typedef __attribute__((ext_vector_type(8))) short short8;
typedef __attribute__((ext_vector_type(4))) float floatx4;

__device__ __forceinline__ float bf2f(u16 u) {
    return __uint_as_float(((unsigned)u) << 16);
}
__device__ __forceinline__ u16 f2bf(float f) {
    unsigned u = __float_as_uint(f);
    return (u16)((u + 0x7FFFu + ((u >> 16) & 1u)) >> 16);
}
__device__ __forceinline__ void load16_to_lds(const void* g, void* l) {
    auto gp = reinterpret_cast<const unsigned int __attribute__((address_space(1)))*>(
        reinterpret_cast<uintptr_t>(g));
    auto lp = reinterpret_cast<unsigned int __attribute__((address_space(3)))*>(
        reinterpret_cast<uintptr_t>(l));
    __builtin_amdgcn_global_load_lds(gp, lp, 16, 0, 0);
}

// ---------------- convert input (fp32 [n,128]) -> xbf cols 0..127 ----------------
__global__ __launch_bounds__(256) void convin_kernel(
    const float* __restrict__ input, u16* __restrict__ xbf, int n)
{
    int gid = blockIdx.x * 256 + threadIdx.x;
    if (gid >= n * 32) return;
    int r = gid >> 5, c4 = (gid & 31) * 4;
    float4 v = *(const float4*)&input[(size_t)r * N_D + c4];
    unsigned p0 = f2bf(v.x) | ((unsigned)f2bf(v.y) << 16);
    unsigned p1 = f2bf(v.z) | ((unsigned)f2bf(v.w) << 16);
    *(uint2*)&xbf[(size_t)r * 256 + c4] = make_uint2(p0, p1);
}

// ---------------- Stage 1: count edges per row ----------------
__global__ __launch_bounds__(256) void count_kernel(
    const int* __restrict__ rows, int* __restrict__ cnt, int E)
{
    int e = blockIdx.x * 256 + threadIdx.x;
    if (e < E) atomicAdd(&cnt[rows[e]], 1);
}

// ---------------- Stage 2: exclusive scan ----------------
__global__ __launch_bounds__(SCAN_B) void scanA_kernel(
    const int* __restrict__ cnt, int* __restrict__ rowPtr,
    int* __restrict__ blockSums, int n)
{
    __shared__ int sm[SCAN_B];
    int t = threadIdx.x;
    int i = blockIdx.x * SCAN_B + t;
    int v = (i < n) ? cnt[i] : 0;
    sm[t] = v;
    __syncthreads();
    for (int off = 1; off < SCAN_B; off <<= 1) {
        int x = (t >= off) ? sm[t - off] : 0;
        __syncthreads();
        sm[t] += x;
        __syncthreads();
    }
    if (i < n) rowPtr[i] = sm[t] - v;
    if (t == SCAN_B - 1) blockSums[blockIdx.x] = sm[t];
}

__global__ __launch_bounds__(128) void scanB_kernel(int* __restrict__ blockSums, int nb)
{
    __shared__ int sm[128];
    int t = threadIdx.x;
    int v = (t < nb) ? blockSums[t] : 0;
    sm[t] = v;
    __syncthreads();
    for (int off = 1; off < 128; off <<= 1) {
        int x = (t >= off) ? sm[t - off] : 0;
        __syncthreads();
        sm[t] += x;
        __syncthreads();
    }
    if (t < nb) blockSums[t] = sm[t] - v;
}

__global__ __launch_bounds__(SCAN_B) void scanC_kernel(
    int* __restrict__ rowPtr, const int* __restrict__ blockSums, int n)
{
    int i = blockIdx.x * SCAN_B + threadIdx.x;
    if (i < n) rowPtr[i] += blockSums[blockIdx.x];
}

// ---------------- Stage 3: scatter edges into CSR order ----------------
__global__ __launch_bounds__(256) void scatter_kernel(
    const int* __restrict__ rows, const int* __restrict__ cols,
    const float* __restrict__ vals, int* __restrict__ rowPtr,
    int* __restrict__ ecol, float* __restrict__ eval, int E)
{
    int e = blockIdx.x * 256 + threadIdx.x;
    if (e >= E) return;
    int r = rows[e];
    int pos = atomicAdd(&rowPtr[r], 1);
    ecol[pos] = cols[e];
    eval[pos] = vals[e];
}

// ---------------- Stage 4: gather-reduce, one wave per row; write bf16 agg half ----------------
__global__ __launch_bounds__(256) void aggregate_kernel(
    const float* __restrict__ input,
    const int* __restrict__ rowPtrEnd, const int* __restrict__ cnt,
    const int* __restrict__ ecol, const float* __restrict__ eval,
    u16* __restrict__ xbf, int n)
{
    int wave = (blockIdx.x * 256 + threadIdx.x) >> 6;
    if (wave >= n) return;
    int lane = threadIdx.x & 63;
    int end = rowPtrEnd[wave];
    int start = end - cnt[wave];
    const float2* inp2 = (const float2*)input;
    float2 acc = make_float2(0.f, 0.f);
    for (int e = start; e < end; ++e) {
        int c = ecol[e];
        float v = eval[e];
        float2 x = inp2[(size_t)c * 64 + lane];
        acc.x += v * x.x;
        acc.y += v * x.y;
    }
    unsigned p = f2bf(acc.x) | ((unsigned)f2bf(acc.y) << 16);
    *((unsigned*)xbf + (size_t)wave * 128 + 64 + lane) = p;
}

// ------------- column sums / sumsq of xbf [n,256] bf16 -------------
__global__ __launch_bounds__(256) void xstats_kernel(
    const u16* __restrict__ xbf, float* __restrict__ sums,
    float* __restrict__ sumsq, int n)
{
    int t = threadIdx.x;
    int r0 = blockIdx.x * STAT_ROWS;
    int r1 = min(n, r0 + STAT_ROWS);
    float s = 0.f, q = 0.f;
    for (int r = r0; r < r1; ++r) {
        float x = bf2f(xbf[(size_t)r * 256 + t]);
        s += x; q += x * x;
    }
    atomicAdd(&sums[t], s);
    atomicAdd(&sumsq[t], q);
}

// ------------- BN1 fold: a1 = rs*gamma1 ; b1' = c1 @ W1 + b1 -------------
__global__ __launch_bounds__(256) void prep1_kernel(
    const float* __restrict__ sums, const float* __restrict__ sumsq,
    const float* __restrict__ gamma1, const float* __restrict__ beta1,
    const float* __restrict__ W1, const float* __restrict__ b1,
    float* __restrict__ a1, float* __restrict__ b1p, float n)
{
    __shared__ float c1s[N_H];
    int t = threadIdx.x;
    float mu = sums[t] / n;
    float var = sumsq[t] / n - mu * mu;
    float rs = rsqrtf(var + EPSV);
    float a = rs * gamma1[t];
    a1[t] = a;
    c1s[t] = beta1[t] - mu * a;
    __syncthreads();
    float acc = b1[t];
    for (int k = 0; k < N_H; ++k)
        acc += c1s[k] * W1[(size_t)k * N_H + t];
    b1p[t] = acc;
}

// ------------- W1bt[nIdx][k] = bf16(a1[k] * W1[k][nIdx]) -------------
__global__ __launch_bounds__(256) void convw1_kernel(
    const float* __restrict__ W1, const float* __restrict__ a1,
    u16* __restrict__ W1bt)
{
    int nIdx = blockIdx.x;
    int k = threadIdx.x;
    W1bt[(size_t)nIdx * 256 + k] = f2bf(a1[k] * W1[(size_t)k * N_H + nIdx]);
}

// ------------- W2bt[nIdx][k] = bf16(W2[k][nIdx]) -------------
__global__ __launch_bounds__(256) void convw2_kernel(
    const float* __restrict__ W2, u16* __restrict__ W2bt)
{
    int nIdx = blockIdx.x;     // 0..127
    int k = threadIdx.x;       // 0..255
    W2bt[(size_t)nIdx * 256 + k] = f2bf(W2[(size_t)k * N_D + nIdx]);
}

// ------------- BN2 per-column affine -------------
__global__ __launch_bounds__(256) void prep2_kernel(
    const float* __restrict__ sums2, const float* __restrict__ sumsq2,
    const float* __restrict__ gamma2, const float* __restrict__ beta2,
    float* __restrict__ a2, float* __restrict__ c2, float n)
{
    int t = threadIdx.x;
    float mu = sums2[t] / n;
    float var = sumsq2[t] / n - mu * mu;
    float rs = rsqrtf(var + EPSV);
    float a = rs * gamma2[t];
    a2[t] = a;
    c2[t] = beta2[t] - mu * a;
}

// ------------- GEMM1 (MFMA): ybf = bf16(xbf @ W1bt^T + b1p), + column stats -------------
// 128x128 tile, BK=32, 4 waves, each wave 4x4 frags of 16x16x32 bf16.
__global__ __launch_bounds__(256) void gemm1_kernel(
    const u16* __restrict__ xbf, const u16* __restrict__ W1bt,
    const float* __restrict__ b1p, u16* __restrict__ ybf,
    float* __restrict__ sums2, float* __restrict__ sumsq2, int n)
{
    __shared__ __align__(16) u16 As[128 * 32];
    __shared__ __align__(16) u16 Bs[128 * 32];
    __shared__ float ssum[128];
    __shared__ float ssq[128];
    int t = threadIdx.x;
    int w = t >> 6, l = t & 63;
    int row0 = blockIdx.x * 128;
    int col0 = blockIdx.y * 128;
    int wrow = (w & 1) * 64, wcol = (w >> 1) * 64;
    int lm = l & 15, lq = l >> 4;
    if (t < 128) { ssum[t] = 0.f; ssq[t] = 0.f; }

    floatx4 acc[4][4];
#pragma unroll
    for (int i = 0; i < 4; ++i)
#pragma unroll
        for (int j = 0; j < 4; ++j) acc[i][j] = (floatx4){0.f, 0.f, 0.f, 0.f};

    for (int k0 = 0; k0 < N_H; k0 += 32) {
#pragma unroll
        for (int i = 0; i < 2; ++i) {
            int rowl = i * 64 + w * 16 + (l >> 2);
            int gcol = k0 + (l & 3) * 8;
            load16_to_lds(&xbf[(size_t)(row0 + rowl) * 256 + gcol],
                          &As[(i * 64 + w * 16) * 32]);
            load16_to_lds(&W1bt[(size_t)(col0 + rowl) * 256 + gcol],
                          &Bs[(i * 64 + w * 16) * 32]);
        }
        __syncthreads();
        short8 a[4], b[4];
#pragma unroll
        for (int f = 0; f < 4; ++f) {
            a[f] = *(const short8*)&As[(wrow + f * 16 + lm) * 32 + lq * 8];
            b[f] = *(const short8*)&Bs[(wcol + f * 16 + lm) * 32 + lq * 8];
        }
#pragma unroll
        for (int fm = 0; fm < 4; ++fm)
#pragma unroll
            for (int fn = 0; fn < 4; ++fn)
                acc[fm][fn] = __builtin_amdgcn_mfma_f32_16x16x32_bf16(
                    a[fm], b[fn], acc[fm][fn], 0, 0, 0);
        __syncthreads();
    }

    // epilogue: +b1p, write bf16 y, accumulate column stats
    float cs[4] = {0.f, 0.f, 0.f, 0.f};
    float cq[4] = {0.f, 0.f, 0.f, 0.f};
#pragma unroll
    for (int fn = 0; fn < 4; ++fn) {
        int c = col0 + wcol + fn * 16 + lm;
        float bb = b1p[c];
#pragma unroll
        for (int fm = 0; fm < 4; ++fm) {
            int rbase = row0 + wrow + fm * 16 + lq * 4;
#pragma unroll
            for (int i = 0; i < 4; ++i) {
                int r = rbase + i;
                if (r < n) {
                    float v = acc[fm][fn][i] + bb;
                    ybf[(size_t)r * 256 + c] = f2bf(v);
                    cs[fn] += v; cq[fn] += v * v;
                }
            }
        }
    }
#pragma unroll
    for (int fn = 0; fn < 4; ++fn) {
        atomicAdd(&ssum[wcol + fn * 16 + lm], cs[fn]);
        atomicAdd(&ssq[wcol + fn * 16 + lm], cq[fn]);
    }
    __syncthreads();
    if (t < 128) {
        atomicAdd(&sums2[col0 + t], ssum[t]);
        atomicAdd(&sumsq2[col0 + t], ssq[t]);
    }
}

// ------------- GEMM2 (MFMA): out = relu(a2*ybf + c2) @ W2bt^T + b2 (fp32 out) -------------
__global__ __launch_bounds__(256) void gemm2_kernel(
    const u16* __restrict__ ybf, const u16* __restrict__ W2bt,
    const float* __restrict__ a2, const float* __restrict__ c2,
    const float* __restrict__ b2, float* __restrict__ out, int n)
{
    __shared__ __align__(16) u16 As[128 * 32];
    __shared__ __align__(16) u16 Bs[128 * 32];
    int t = threadIdx.x;
    int w = t >> 6, l = t & 63;
    int row0 = blockIdx.x * 128;
    int wrow = (w & 1) * 64, wcol = (w >> 1) * 64;
    int lm = l & 15, lq = l >> 4;

    floatx4 acc[4][4];
#pragma unroll
    for (int i = 0; i < 4; ++i)
#pragma unroll
        for (int j = 0; j < 4; ++j) acc[i][j] = (floatx4){0.f, 0.f, 0.f, 0.f};

    for (int k0 = 0; k0 < N_H; k0 += 32) {
        // B: global_load_lds direct
#pragma unroll
        for (int i = 0; i < 2; ++i) {
            int rowl = i * 64 + w * 16 + (l >> 2);
            int gcol = k0 + (l & 3) * 8;
            load16_to_lds(&W2bt[(size_t)rowl * 256 + gcol],
                          &Bs[(i * 64 + w * 16) * 32]);
        }
        // A: load ybf, apply BN2 affine + relu, convert to bf16, ds_write
        int kc = k0 + (t & 3) * 8;
        float4 aa0 = *(const float4*)&a2[kc];
        float4 aa1 = *(const float4*)&a2[kc + 4];
        float4 cc0 = *(const float4*)&c2[kc];
        float4 cc1 = *(const float4*)&c2[kc + 4];
#pragma unroll
        for (int i = 0; i < 2; ++i) {
            int rowl = i * 64 + (t >> 2);
            uint4 raw = *(const uint4*)&ybf[(size_t)(row0 + rowl) * 256 + kc];
            float z0 = fmaxf(bf2f(raw.x & 0xFFFF) * aa0.x + cc0.x, 0.f);
            float z1 = fmaxf(bf2f(raw.x >> 16)    * aa0.y + cc0.y, 0.f);
            float z2 = fmaxf(bf2f(raw.y & 0xFFFF) * aa0.z + cc0.z, 0.f);
            float z3 = fmaxf(bf2f(raw.y >> 16)    * aa0.w + cc0.w, 0.f);
            float z4 = fmaxf(bf2f(raw.z & 0xFFFF) * aa1.x + cc1.x, 0.f);
            float z5 = fmaxf(bf2f(raw.z >> 16)    * aa1.y + cc1.y, 0.f);
            float z6 = fmaxf(bf2f(raw.w & 0xFFFF) * aa1.z + cc1.z, 0.f);
            float z7 = fmaxf(bf2f(raw.w >> 16)    * aa1.w + cc1.w, 0.f);
            uint4 pk;
            pk.x = f2bf(z0) | ((unsigned)f2bf(z1) << 16);
            pk.y = f2bf(z2) | ((unsigned)f2bf(z3) << 16);
            pk.z = f2bf(z4) | ((unsigned)f2bf(z5) << 16);
            pk.w = f2bf(z6) | ((unsigned)f2bf(z7) << 16);
            *(uint4*)&As[rowl * 32 + (t & 3) * 8] = pk;
        }
        __syncthreads();
        short8 a[4], b[4];
#pragma unroll
        for (int f = 0; f < 4; ++f) {
            a[f] = *(const short8*)&As[(wrow + f * 16 + lm) * 32 + lq * 8];
            b[f] = *(const short8*)&Bs[(wcol + f * 16 + lm) * 32 + lq * 8];
        }
#pragma unroll
        for (int fm = 0; fm < 4; ++fm)
#pragma unroll
            for (int fn = 0; fn < 4; ++fn)
                acc[fm][fn] = __builtin_amdgcn_mfma_f32_16x16x32_bf16(
                    a[fm], b[fn], acc[fm][fn], 0, 0, 0);
        __syncthreads();
    }

#pragma unroll
    for (int fn = 0; fn < 4; ++fn) {
        int c = wcol + fn * 16 + lm;
        float bb = b2[c];
#pragma unroll
        for (int fm = 0; fm < 4; ++fm) {
            int rbase = row0 + wrow + fm * 16 + lq * 4;
#pragma unroll
            for (int i = 0; i < 4; ++i) {
                int r = rbase + i;
                if (r < n) out[(size_t)r * N_D + c] = acc[fm][fn][i] + bb;
            }
        }
    }
}

extern "C" void kernel_launch(void* const* d_in, const int* in_sizes, int n_in,
                              void* d_out, int out_size, void* d_ws, size_t ws_size,
                              hipStream_t stream)
{
    const float* input    = (const float*)d_in[0];
    const int*   adj_rows = (const int*)d_in[1];
    const int*   adj_cols = (const int*)d_in[2];
    const float* adj_vals = (const float*)d_in[3];
    const float* gamma1   = (const float*)d_in[4];
    const float* beta1    = (const float*)d_in[5];
    const float* W1       = (const float*)d_in[6];
    const float* b1       = (const float*)d_in[7];
    const float* gamma2   = (const float*)d_in[8];
    const float* beta2    = (const float*)d_in[9];
    const float* W2       = (const float*)d_in[10];
    const float* b2       = (const float*)d_in[11];

    int n = in_sizes[0] / N_D;   // 100000
    int E = in_sizes[1];         // 1600000
    size_t n_pad = ((size_t)n + 127) & ~(size_t)127;

    u16* xbf = (u16*)d_ws;                         // n_pad*256 bf16
    u16* ybf = xbf + n_pad * 256;                  // n_pad*256 bf16
    // CSR edge arrays alias ybf (consumed by aggregate before gemm1 writes ybf)
    int*   ecol  = (int*)ybf;                      // E ints
    float* eval_ = (float*)ybf + E;                // E floats
    u16* W1bt = ybf + n_pad * 256;                 // 256*256 bf16
    u16* W2bt = W1bt + 256 * 256;                  // 128*256 bf16
    float* stats  = (float*)(W2bt + 128 * 256);
    float* sums1  = stats;
    float* sumsq1 = stats + 256;
    float* a1     = stats + 512;
    float* b1p    = stats + 768;
    float* sums2  = stats + 1024;
    float* sumsq2 = stats + 1280;
    float* a2     = stats + 1536;
    float* c2     = stats + 1792;
    int* cnt       = (int*)(stats + 2048);
    int* rowPtr    = cnt + n;
    int* blockSums = rowPtr + n;

    hipMemsetAsync(cnt, 0, (size_t)n * sizeof(int), stream);
    hipMemsetAsync(stats, 0, 2048 * sizeof(float), stream);

    convin_kernel<<<(n * 32 + 255) / 256, 256, 0, stream>>>(input, xbf, n);
    convw2_kernel<<<128, 256, 0, stream>>>(W2, W2bt);

    int eb = (E + 255) / 256;
    count_kernel<<<eb, 256, 0, stream>>>(adj_rows, cnt, E);

    int nb = (n + SCAN_B - 1) / SCAN_B;
    scanA_kernel<<<nb, SCAN_B, 0, stream>>>(cnt, rowPtr, blockSums, n);
    scanB_kernel<<<1, 128, 0, stream>>>(blockSums, nb);
    scanC_kernel<<<nb, SCAN_B, 0, stream>>>(rowPtr, blockSums, n);

    scatter_kernel<<<eb, 256, 0, stream>>>(adj_rows, adj_cols, adj_vals, rowPtr, ecol, eval_, E);

    aggregate_kernel<<<(n + 3) / 4, 256, 0, stream>>>(input, rowPtr, cnt, ecol, eval_, xbf, n);

    xstats_kernel<<<(n + STAT_ROWS - 1) / STAT_ROWS, 256, 0, stream>>>(xbf, sums1, sumsq1, n);

    prep1_kernel<<<1, 256, 0, stream>>>(sums1, sumsq1, gamma1, beta1, W1, b1, a1, b1p, (float)n);
    convw1_kernel<<<256, 256, 0, stream>>>(W1, a1, W1bt);

    dim3 g1((unsigned)(n_pad / 128), 2);
    gemm1_kernel<<<g1, 256, 0, stream>>>(xbf, W1bt, b1p, ybf, sums2, sumsq2, n);

    prep2_kernel<<<1, 256, 0, stream>>>(sums2, sumsq2, gamma2, beta2, a2, c2, (float)n);

    gemm2_kernel<<<(unsigned)(n_pad / 128), 256, 0, stream>>>(ybf, W2bt, a2, c2, b2, (float*)d_out, n);
}

// Round 4
// 596.576 us; speedup vs baseline: 5.3986x; 1.1418x over previous
//
#include <hip/hip_runtime.h>

#define N_D 128
#define N_H 256
#define EPSV 1e-5f
#define STAT_ROWS 256
#define SCAN_B 1024

typedef unsigned short u16;
typedef __attribute__((ext_vector_type(8))) short short8;
typedef __attribute__((ext_vector_type(4))) float floatx4;

__device__ __forceinline__ float bf2f(unsigned u) {
    return __uint_as_float(u << 16);
}
__device__ __forceinline__ u16 f2bf(float f) {
    unsigned u = __float_as_uint(f);
    return (u16)((u + 0x7FFFu + ((u >> 16) & 1u)) >> 16);
}
__device__ __forceinline__ void load16_to_lds(const void* g, void* l) {
    auto gp = reinterpret_cast<const unsigned int __attribute__((address_space(1)))*>(
        reinterpret_cast<uintptr_t>(g));
    auto lp = reinterpret_cast<unsigned int __attribute__((address_space(3)))*>(
        reinterpret_cast<uintptr_t>(l));
    __builtin_amdgcn_global_load_lds(gp, lp, 16, 0, 0);
}

// ------- convert input fp32 -> xbf cols 0..127 (bf16), fused edge count -------
__global__ __launch_bounds__(256) void convin_count_kernel(
    const float* __restrict__ input, u16* __restrict__ xbf,
    const int* __restrict__ rows, int* __restrict__ cnt, int n, int E)
{
    int gid = blockIdx.x * 256 + threadIdx.x;
    if (gid < n * 32) {
        int r = gid >> 5, c4 = (gid & 31) * 4;
        float4 v = *(const float4*)&input[(size_t)r * N_D + c4];
        unsigned p0 = f2bf(v.x) | ((unsigned)f2bf(v.y) << 16);
        unsigned p1 = f2bf(v.z) | ((unsigned)f2bf(v.w) << 16);
        *(uint2*)&xbf[(size_t)r * 256 + c4] = make_uint2(p0, p1);
    }
    if (gid < E) atomicAdd(&cnt[rows[gid]], 1);
}

// ---------------- exclusive scan ----------------
__global__ __launch_bounds__(SCAN_B) void scanA_kernel(
    const int* __restrict__ cnt, int* __restrict__ rowPtr,
    int* __restrict__ blockSums, int n)
{
    __shared__ int sm[SCAN_B];
    int t = threadIdx.x;
    int i = blockIdx.x * SCAN_B + t;
    int v = (i < n) ? cnt[i] : 0;
    sm[t] = v;
    __syncthreads();
    for (int off = 1; off < SCAN_B; off <<= 1) {
        int x = (t >= off) ? sm[t - off] : 0;
        __syncthreads();
        sm[t] += x;
        __syncthreads();
    }
    if (i < n) rowPtr[i] = sm[t] - v;
    if (t == SCAN_B - 1) blockSums[blockIdx.x] = sm[t];
}

__global__ __launch_bounds__(128) void scanB_kernel(int* __restrict__ blockSums, int nb)
{
    __shared__ int sm[128];
    int t = threadIdx.x;
    int v = (t < nb) ? blockSums[t] : 0;
    sm[t] = v;
    __syncthreads();
    for (int off = 1; off < 128; off <<= 1) {
        int x = (t >= off) ? sm[t - off] : 0;
        __syncthreads();
        sm[t] += x;
        __syncthreads();
    }
    if (t < nb) blockSums[t] = sm[t] - v;
}

__global__ __launch_bounds__(SCAN_B) void scanC_kernel(
    int* __restrict__ rowPtr, const int* __restrict__ blockSums, int n)
{
    int i = blockIdx.x * SCAN_B + threadIdx.x;
    if (i < n) rowPtr[i] += blockSums[blockIdx.x];
}

// ---------------- scatter edges into CSR order, packed int2 {col, val} ----------------
__global__ __launch_bounds__(256) void scatter_kernel(
    const int* __restrict__ rows, const int* __restrict__ cols,
    const float* __restrict__ vals, int* __restrict__ rowPtr,
    int2* __restrict__ edges, int E)
{
    int e = blockIdx.x * 256 + threadIdx.x;
    if (e >= E) return;
    int r = rows[e];
    int pos = atomicAdd(&rowPtr[r], 1);
    edges[pos] = make_int2(cols[e], __float_as_int(vals[e]));
}

// ------- gather-reduce (bf16 gathers), one wave per row, write bf16 agg half -------
__global__ __launch_bounds__(256) void aggregate_kernel(
    const unsigned* __restrict__ xin,          // xbf viewed as uint; row stride 128
    const int* __restrict__ rowPtrEnd, const int* __restrict__ cnt,
    const int2* __restrict__ edges,
    unsigned* __restrict__ xout, int n)        // same buffer; agg half at +64
{
    int wave = (blockIdx.x * 256 + threadIdx.x) >> 6;
    if (wave >= n) return;
    int lane = threadIdx.x & 63;
    int end = rowPtrEnd[wave];
    int e = end - cnt[wave];
    float2 acc0 = make_float2(0.f, 0.f);
    float2 acc1 = make_float2(0.f, 0.f);
    for (; e + 1 < end; e += 2) {
        int2 e0 = edges[e];
        int2 e1 = edges[e + 1];
        unsigned p0 = xin[(size_t)e0.x * 128 + lane];
        unsigned p1 = xin[(size_t)e1.x * 128 + lane];
        float v0 = __int_as_float(e0.y);
        float v1 = __int_as_float(e1.y);
        acc0.x += v0 * bf2f(p0 & 0xFFFF);
        acc0.y += v0 * bf2f(p0 >> 16);
        acc1.x += v1 * bf2f(p1 & 0xFFFF);
        acc1.y += v1 * bf2f(p1 >> 16);
    }
    if (e < end) {
        int2 e0 = edges[e];
        unsigned p0 = xin[(size_t)e0.x * 128 + lane];
        float v0 = __int_as_float(e0.y);
        acc0.x += v0 * bf2f(p0 & 0xFFFF);
        acc0.y += v0 * bf2f(p0 >> 16);
    }
    acc0.x += acc1.x;
    acc0.y += acc1.y;
    xout[(size_t)wave * 128 + 64 + lane] = f2bf(acc0.x) | ((unsigned)f2bf(acc0.y) << 16);
}

// ------------- column sums / sumsq of xbf [n,256] bf16 -------------
__global__ __launch_bounds__(256) void xstats_kernel(
    const u16* __restrict__ xbf, float* __restrict__ sums,
    float* __restrict__ sumsq, int n)
{
    int t = threadIdx.x;
    int r0 = blockIdx.x * STAT_ROWS;
    int r1 = min(n, r0 + STAT_ROWS);
    float s = 0.f, q = 0.f;
    for (int r = r0; r < r1; ++r) {
        float x = bf2f((unsigned)xbf[(size_t)r * 256 + t]);
        s += x; q += x * x;
    }
    atomicAdd(&sums[t], s);
    atomicAdd(&sumsq[t], q);
}

// ------------- BN1 affine coefficients: a1 = rs*gamma1 ; c1 = beta1 - mu*a1 -------------
__global__ __launch_bounds__(256) void prep1a_kernel(
    const float* __restrict__ sums, const float* __restrict__ sumsq,
    const float* __restrict__ gamma1, const float* __restrict__ beta1,
    float* __restrict__ a1, float* __restrict__ c1, float n)
{
    int t = threadIdx.x;
    float mu = sums[t] / n;
    float var = sumsq[t] / n - mu * mu;
    float rs = rsqrtf(var + EPSV);
    float a = rs * gamma1[t];
    a1[t] = a;
    c1[t] = beta1[t] - mu * a;
}

// ------- W1bt[nIdx][k] = bf16(a1[k]*W1[k][nIdx]) ; b1p[nIdx] = c1@W1[:,nIdx] + b1 -------
__global__ __launch_bounds__(256) void convw1_kernel(
    const float* __restrict__ W1, const float* __restrict__ a1,
    const float* __restrict__ c1, const float* __restrict__ b1,
    u16* __restrict__ W1bt, float* __restrict__ b1p)
{
    __shared__ float red[256];
    int nIdx = blockIdx.x;
    int k = threadIdx.x;
    float w = W1[(size_t)k * N_H + nIdx];
    W1bt[(size_t)nIdx * 256 + k] = f2bf(a1[k] * w);
    red[k] = c1[k] * w;
    __syncthreads();
    for (int s = 128; s > 0; s >>= 1) {
        if (k < s) red[k] += red[k + s];
        __syncthreads();
    }
    if (k == 0) b1p[nIdx] = red[0] + b1[nIdx];
}

// ------------- W2bt[nIdx][k] = bf16(W2[k][nIdx]) -------------
__global__ __launch_bounds__(256) void convw2_kernel(
    const float* __restrict__ W2, u16* __restrict__ W2bt)
{
    int nIdx = blockIdx.x;
    int k = threadIdx.x;
    W2bt[(size_t)nIdx * 256 + k] = f2bf(W2[(size_t)k * N_D + nIdx]);
}

// ------------- BN2 per-column affine -------------
__global__ __launch_bounds__(256) void prep2_kernel(
    const float* __restrict__ sums2, const float* __restrict__ sumsq2,
    const float* __restrict__ gamma2, const float* __restrict__ beta2,
    float* __restrict__ a2, float* __restrict__ c2, float n)
{
    int t = threadIdx.x;
    float mu = sums2[t] / n;
    float var = sumsq2[t] / n - mu * mu;
    float rs = rsqrtf(var + EPSV);
    float a = rs * gamma2[t];
    a2[t] = a;
    c2[t] = beta2[t] - mu * a;
}

// ------------- GEMM1 (MFMA): ybf = bf16(xbf @ W1bt^T + b1p), + column stats -------------
__global__ __launch_bounds__(256) void gemm1_kernel(
    const u16* __restrict__ xbf, const u16* __restrict__ W1bt,
    const float* __restrict__ b1p, u16* __restrict__ ybf,
    float* __restrict__ sums2, float* __restrict__ sumsq2, int n)
{
    __shared__ __align__(16) u16 As[128 * 32];
    __shared__ __align__(16) u16 Bs[128 * 32];
    __shared__ float ssum[128];
    __shared__ float ssq[128];
    int t = threadIdx.x;
    int w = t >> 6, l = t & 63;
    int row0 = blockIdx.x * 128;
    int col0 = blockIdx.y * 128;
    int wrow = (w & 1) * 64, wcol = (w >> 1) * 64;
    int lm = l & 15, lq = l >> 4;
    if (t < 128) { ssum[t] = 0.f; ssq[t] = 0.f; }

    floatx4 acc[4][4];
#pragma unroll
    for (int i = 0; i < 4; ++i)
#pragma unroll
        for (int j = 0; j < 4; ++j) acc[i][j] = (floatx4){0.f, 0.f, 0.f, 0.f};

    for (int k0 = 0; k0 < N_H; k0 += 32) {
#pragma unroll
        for (int i = 0; i < 2; ++i) {
            int rowl = i * 64 + w * 16 + (l >> 2);
            int gcol = k0 + (l & 3) * 8;
            load16_to_lds(&xbf[(size_t)(row0 + rowl) * 256 + gcol],
                          &As[(i * 64 + w * 16) * 32]);
            load16_to_lds(&W1bt[(size_t)(col0 + rowl) * 256 + gcol],
                          &Bs[(i * 64 + w * 16) * 32]);
        }
        __syncthreads();
        short8 a[4], b[4];
#pragma unroll
        for (int f = 0; f < 4; ++f) {
            a[f] = *(const short8*)&As[(wrow + f * 16 + lm) * 32 + lq * 8];
            b[f] = *(const short8*)&Bs[(wcol + f * 16 + lm) * 32 + lq * 8];
        }
#pragma unroll
        for (int fm = 0; fm < 4; ++fm)
#pragma unroll
            for (int fn = 0; fn < 4; ++fn)
                acc[fm][fn] = __builtin_amdgcn_mfma_f32_16x16x32_bf16(
                    a[fm], b[fn], acc[fm][fn], 0, 0, 0);
        __syncthreads();
    }

    float cs[4] = {0.f, 0.f, 0.f, 0.f};
    float cq[4] = {0.f, 0.f, 0.f, 0.f};
#pragma unroll
    for (int fn = 0; fn < 4; ++fn) {
        int c = col0 + wcol + fn * 16 + lm;
        float bb = b1p[c];
#pragma unroll
        for (int fm = 0; fm < 4; ++fm) {
            int rbase = row0 + wrow + fm * 16 + lq * 4;
#pragma unroll
            for (int i = 0; i < 4; ++i) {
                int r = rbase + i;
                if (r < n) {
                    float v = acc[fm][fn][i] + bb;
                    ybf[(size_t)r * 256 + c] = f2bf(v);
                    cs[fn] += v; cq[fn] += v * v;
                }
            }
        }
    }
#pragma unroll
    for (int fn = 0; fn < 4; ++fn) {
        atomicAdd(&ssum[wcol + fn * 16 + lm], cs[fn]);
        atomicAdd(&ssq[wcol + fn * 16 + lm], cq[fn]);
    }
    __syncthreads();
    if (t < 128) {
        atomicAdd(&sums2[col0 + t], ssum[t]);
        atomicAdd(&sumsq2[col0 + t], ssq[t]);
    }
}

// ------------- GEMM2 (MFMA): out = relu(a2*ybf + c2) @ W2bt^T + b2 (fp32 out) -------------
__global__ __launch_bounds__(256) void gemm2_kernel(
    const u16* __restrict__ ybf, const u16* __restrict__ W2bt,
    const float* __restrict__ a2, const float* __restrict__ c2,
    const float* __restrict__ b2, float* __restrict__ out, int n)
{
    __shared__ __align__(16) u16 As[128 * 32];
    __shared__ __align__(16) u16 Bs[128 * 32];
    int t = threadIdx.x;
    int w = t >> 6, l = t & 63;
    int row0 = blockIdx.x * 128;
    int wrow = (w & 1) * 64, wcol = (w >> 1) * 64;
    int lm = l & 15, lq = l >> 4;

    floatx4 acc[4][4];
#pragma unroll
    for (int i = 0; i < 4; ++i)
#pragma unroll
        for (int j = 0; j < 4; ++j) acc[i][j] = (floatx4){0.f, 0.f, 0.f, 0.f};

    for (int k0 = 0; k0 < N_H; k0 += 32) {
#pragma unroll
        for (int i = 0; i < 2; ++i) {
            int rowl = i * 64 + w * 16 + (l >> 2);
            int gcol = k0 + (l & 3) * 8;
            load16_to_lds(&W2bt[(size_t)rowl * 256 + gcol],
                          &Bs[(i * 64 + w * 16) * 32]);
        }
        int kc = k0 + (t & 3) * 8;
        float4 aa0 = *(const float4*)&a2[kc];
        float4 aa1 = *(const float4*)&a2[kc + 4];
        float4 cc0 = *(const float4*)&c2[kc];
        float4 cc1 = *(const float4*)&c2[kc + 4];
#pragma unroll
        for (int i = 0; i < 2; ++i) {
            int rowl = i * 64 + (t >> 2);
            uint4 raw = *(const uint4*)&ybf[(size_t)(row0 + rowl) * 256 + kc];
            float z0 = fmaxf(bf2f(raw.x & 0xFFFF) * aa0.x + cc0.x, 0.f);
            float z1 = fmaxf(bf2f(raw.x >> 16)    * aa0.y + cc0.y, 0.f);
            float z2 = fmaxf(bf2f(raw.y & 0xFFFF) * aa0.z + cc0.z, 0.f);
            float z3 = fmaxf(bf2f(raw.y >> 16)    * aa0.w + cc0.w, 0.f);
            float z4 = fmaxf(bf2f(raw.z & 0xFFFF) * aa1.x + cc1.x, 0.f);
            float z5 = fmaxf(bf2f(raw.z >> 16)    * aa1.y + cc1.y, 0.f);
            float z6 = fmaxf(bf2f(raw.w & 0xFFFF) * aa1.z + cc1.z, 0.f);
            float z7 = fmaxf(bf2f(raw.w >> 16)    * aa1.w + cc1.w, 0.f);
            uint4 pk;
            pk.x = f2bf(z0) | ((unsigned)f2bf(z1) << 16);
            pk.y = f2bf(z2) | ((unsigned)f2bf(z3) << 16);
            pk.z = f2bf(z4) | ((unsigned)f2bf(z5) << 16);
            pk.w = f2bf(z6) | ((unsigned)f2bf(z7) << 16);
            *(uint4*)&As[rowl * 32 + (t & 3) * 8] = pk;
        }
        __syncthreads();
        short8 a[4], b[4];
#pragma unroll
        for (int f = 0; f < 4; ++f) {
            a[f] = *(const short8*)&As[(wrow + f * 16 + lm) * 32 + lq * 8];
            b[f] = *(const short8*)&Bs[(wcol + f * 16 + lm) * 32 + lq * 8];
        }
#pragma unroll
        for (int fm = 0; fm < 4; ++fm)
#pragma unroll
            for (int fn = 0; fn < 4; ++fn)
                acc[fm][fn] = __builtin_amdgcn_mfma_f32_16x16x32_bf16(
                    a[fm], b[fn], acc[fm][fn], 0, 0, 0);
        __syncthreads();
    }

#pragma unroll
    for (int fn = 0; fn < 4; ++fn) {
        int c = wcol + fn * 16 + lm;
        float bb = b2[c];
#pragma unroll
        for (int fm = 0; fm < 4; ++fm) {
            int rbase = row0 + wrow + fm * 16 + lq * 4;
#pragma unroll
            for (int i = 0; i < 4; ++i) {
                int r = rbase + i;
                if (r < n) out[(size_t)r * N_D + c] = acc[fm][fn][i] + bb;
            }
        }
    }
}

extern "C" void kernel_launch(void* const* d_in, const int* in_sizes, int n_in,
                              void* d_out, int out_size, void* d_ws, size_t ws_size,
                              hipStream_t stream)
{
    const float* input    = (const float*)d_in[0];
    const int*   adj_rows = (const int*)d_in[1];
    const int*   adj_cols = (const int*)d_in[2];
    const float* adj_vals = (const float*)d_in[3];
    const float* gamma1   = (const float*)d_in[4];
    const float* beta1    = (const float*)d_in[5];
    const float* W1       = (const float*)d_in[6];
    const float* b1       = (const float*)d_in[7];
    const float* gamma2   = (const float*)d_in[8];
    const float* beta2    = (const float*)d_in[9];
    const float* W2       = (const float*)d_in[10];
    const float* b2       = (const float*)d_in[11];

    int n = in_sizes[0] / N_D;   // 100000
    int E = in_sizes[1];         // 1600000
    size_t n_pad = ((size_t)n + 127) & ~(size_t)127;

    u16* xbf = (u16*)d_ws;                         // n_pad*256 bf16
    u16* ybf = xbf + n_pad * 256;                  // n_pad*256 bf16
    int2* edges = (int2*)ybf;                      // E int2 (aliases ybf; consumed pre-gemm1)
    u16* W1bt = ybf + n_pad * 256;                 // 256*256 bf16
    u16* W2bt = W1bt + 256 * 256;                  // 128*256 bf16
    float* stats  = (float*)(W2bt + 128 * 256);
    float* sums1  = stats;
    float* sumsq1 = stats + 256;
    float* a1     = stats + 512;
    float* b1p    = stats + 768;
    float* sums2  = stats + 1024;
    float* sumsq2 = stats + 1280;
    float* a2     = stats + 1536;
    float* c2     = stats + 1792;
    float* c1     = stats + 2048;
    int* cnt       = (int*)(stats + 2304);
    int* rowPtr    = cnt + n;
    int* blockSums = rowPtr + n;

    hipMemsetAsync(cnt, 0, (size_t)n * sizeof(int), stream);
    hipMemsetAsync(stats, 0, 2048 * sizeof(float), stream);

    convin_count_kernel<<<(n * 32 + 255) / 256, 256, 0, stream>>>(
        input, xbf, adj_rows, cnt, n, E);
    convw2_kernel<<<128, 256, 0, stream>>>(W2, W2bt);

    int nb = (n + SCAN_B - 1) / SCAN_B;
    scanA_kernel<<<nb, SCAN_B, 0, stream>>>(cnt, rowPtr, blockSums, n);
    scanB_kernel<<<1, 128, 0, stream>>>(blockSums, nb);
    scanC_kernel<<<nb, SCAN_B, 0, stream>>>(rowPtr, blockSums, n);

    int eb = (E + 255) / 256;
    scatter_kernel<<<eb, 256, 0, stream>>>(adj_rows, adj_cols, adj_vals, rowPtr, edges, E);

    aggregate_kernel<<<(n + 3) / 4, 256, 0, stream>>>(
        (const unsigned*)xbf, rowPtr, cnt, edges, (unsigned*)xbf, n);

    xstats_kernel<<<(n + STAT_ROWS - 1) / STAT_ROWS, 256, 0, stream>>>(xbf, sums1, sumsq1, n);

    prep1a_kernel<<<1, 256, 0, stream>>>(sums1, sumsq1, gamma1, beta1, a1, c1, (float)n);
    convw1_kernel<<<256, 256, 0, stream>>>(W1, a1, c1, b1, W1bt, b1p);

    dim3 g1((unsigned)(n_pad / 128), 2);
    gemm1_kernel<<<g1, 256, 0, stream>>>(xbf, W1bt, b1p, ybf, sums2, sumsq2, n);

    prep2_kernel<<<1, 256, 0, stream>>>(sums2, sumsq2, gamma2, beta2, a2, c2, (float)n);

    gemm2_kernel<<<(unsigned)(n_pad / 128), 256, 0, stream>>>(ybf, W2bt, a2, c2, b2, (float*)d_out, n);
}

// Round 5
// 584.002 us; speedup vs baseline: 5.5148x; 1.0215x over previous
//
#include <hip/hip_runtime.h>

#define N_D 128
#define N_H 256
#define EPSV 1e-5f
#define STAT_ROWS 256
#define SCAN_B 1024

typedef unsigned short u16;
typedef __attribute__((ext_vector_type(8))) short short8;
typedef __attribute__((ext_vector_type(4))) float floatx4;

__device__ __forceinline__ float bf2f(unsigned u) {
    return __uint_as_float(u << 16);
}
__device__ __forceinline__ u16 f2bf(float f) {
    unsigned u = __float_as_uint(f);
    return (u16)((u + 0x7FFFu + ((u >> 16) & 1u)) >> 16);
}
__device__ __forceinline__ void load16_to_lds(const void* g, void* l) {
    auto gp = reinterpret_cast<const unsigned int __attribute__((address_space(1)))*>(
        reinterpret_cast<uintptr_t>(g));
    auto lp = reinterpret_cast<unsigned int __attribute__((address_space(3)))*>(
        reinterpret_cast<uintptr_t>(l));
    __builtin_amdgcn_global_load_lds(gp, lp, 16, 0, 0);
}

// ------- convert input fp32 -> xbf cols 0..127 (bf16), fused edge count -------
__global__ __launch_bounds__(256) void convin_count_kernel(
    const float* __restrict__ input, u16* __restrict__ xbf,
    const int* __restrict__ rows, int* __restrict__ cnt, int n, int E)
{
    int gid = blockIdx.x * 256 + threadIdx.x;
    if (gid < n * 32) {
        int r = gid >> 5, c4 = (gid & 31) * 4;
        float4 v = *(const float4*)&input[(size_t)r * N_D + c4];
        unsigned p0 = f2bf(v.x) | ((unsigned)f2bf(v.y) << 16);
        unsigned p1 = f2bf(v.z) | ((unsigned)f2bf(v.w) << 16);
        *(uint2*)&xbf[(size_t)r * 256 + c4] = make_uint2(p0, p1);
    }
    if (gid < E) atomicAdd(&cnt[rows[gid]], 1);
}

// ---------------- exclusive scan ----------------
__global__ __launch_bounds__(SCAN_B) void scanA_kernel(
    const int* __restrict__ cnt, int* __restrict__ rowPtr,
    int* __restrict__ blockSums, int n)
{
    __shared__ int sm[SCAN_B];
    int t = threadIdx.x;
    int i = blockIdx.x * SCAN_B + t;
    int v = (i < n) ? cnt[i] : 0;
    sm[t] = v;
    __syncthreads();
    for (int off = 1; off < SCAN_B; off <<= 1) {
        int x = (t >= off) ? sm[t - off] : 0;
        __syncthreads();
        sm[t] += x;
        __syncthreads();
    }
    if (i < n) rowPtr[i] = sm[t] - v;
    if (t == SCAN_B - 1) blockSums[blockIdx.x] = sm[t];
}

__global__ __launch_bounds__(128) void scanB_kernel(int* __restrict__ blockSums, int nb)
{
    __shared__ int sm[128];
    int t = threadIdx.x;
    int v = (t < nb) ? blockSums[t] : 0;
    sm[t] = v;
    __syncthreads();
    for (int off = 1; off < 128; off <<= 1) {
        int x = (t >= off) ? sm[t - off] : 0;
        __syncthreads();
        sm[t] += x;
        __syncthreads();
    }
    if (t < nb) blockSums[t] = sm[t] - v;
}

__global__ __launch_bounds__(SCAN_B) void scanC_kernel(
    int* __restrict__ rowPtr, const int* __restrict__ blockSums, int n)
{
    int i = blockIdx.x * SCAN_B + threadIdx.x;
    if (i < n) rowPtr[i] += blockSums[blockIdx.x];
}

// ------- XCD-colored scatter: color c = row & 7 handled only by blocks with
// blockIdx & 7 == c (round-robin dispatch pins color -> XCD, so all partial
// writes of a CSR cacheline merge in ONE XCD's L2 -> 1 writeback, not ~8).
__global__ __launch_bounds__(256) void scatter_kernel(
    const int* __restrict__ rows, const int* __restrict__ cols,
    const float* __restrict__ vals, int* __restrict__ rowPtr,
    int2* __restrict__ edges, int E)
{
    int c = blockIdx.x & 7;
    int s = blockIdx.x >> 3;
    int nseg = gridDim.x >> 3;
    int per = (E + nseg - 1) / nseg;
    int lo = s * per;
    int hi = min(E, lo + per);
    for (int e = lo + threadIdx.x; e < hi; e += 256) {
        int r = rows[e];
        if ((r & 7) == c) {
            int pos = atomicAdd(&rowPtr[r], 1);
            edges[pos] = make_int2(cols[e], __float_as_int(vals[e]));
        }
    }
}

// ------- gather-reduce (bf16 gathers), one wave per row, write bf16 agg half -------
__global__ __launch_bounds__(256) void aggregate_kernel(
    const unsigned* __restrict__ xin,          // xbf viewed as uint; row stride 128
    const int* __restrict__ rowPtrEnd, const int* __restrict__ cnt,
    const int2* __restrict__ edges,
    unsigned* __restrict__ xout, int n)        // same buffer; agg half at +64
{
    int wave = (blockIdx.x * 256 + threadIdx.x) >> 6;
    if (wave >= n) return;
    int lane = threadIdx.x & 63;
    int end = rowPtrEnd[wave];
    int e = end - cnt[wave];
    float2 acc0 = make_float2(0.f, 0.f);
    float2 acc1 = make_float2(0.f, 0.f);
    for (; e + 1 < end; e += 2) {
        int2 e0 = edges[e];
        int2 e1 = edges[e + 1];
        unsigned p0 = xin[(size_t)e0.x * 128 + lane];
        unsigned p1 = xin[(size_t)e1.x * 128 + lane];
        float v0 = __int_as_float(e0.y);
        float v1 = __int_as_float(e1.y);
        acc0.x += v0 * bf2f(p0 & 0xFFFF);
        acc0.y += v0 * bf2f(p0 >> 16);
        acc1.x += v1 * bf2f(p1 & 0xFFFF);
        acc1.y += v1 * bf2f(p1 >> 16);
    }
    if (e < end) {
        int2 e0 = edges[e];
        unsigned p0 = xin[(size_t)e0.x * 128 + lane];
        float v0 = __int_as_float(e0.y);
        acc0.x += v0 * bf2f(p0 & 0xFFFF);
        acc0.y += v0 * bf2f(p0 >> 16);
    }
    acc0.x += acc1.x;
    acc0.y += acc1.y;
    xout[(size_t)wave * 128 + 64 + lane] = f2bf(acc0.x) | ((unsigned)f2bf(acc0.y) << 16);
}

// ------------- column sums / sumsq of xbf [n,256] bf16 -------------
__global__ __launch_bounds__(256) void xstats_kernel(
    const u16* __restrict__ xbf, float* __restrict__ sums,
    float* __restrict__ sumsq, int n)
{
    int t = threadIdx.x;
    int r0 = blockIdx.x * STAT_ROWS;
    int r1 = min(n, r0 + STAT_ROWS);
    float s = 0.f, q = 0.f;
    for (int r = r0; r < r1; ++r) {
        float x = bf2f((unsigned)xbf[(size_t)r * 256 + t]);
        s += x; q += x * x;
    }
    atomicAdd(&sums[t], s);
    atomicAdd(&sumsq[t], q);
}

// ------------- BN1 affine coefficients: a1 = rs*gamma1 ; c1 = beta1 - mu*a1 -------------
__global__ __launch_bounds__(256) void prep1a_kernel(
    const float* __restrict__ sums, const float* __restrict__ sumsq,
    const float* __restrict__ gamma1, const float* __restrict__ beta1,
    float* __restrict__ a1, float* __restrict__ c1, float n)
{
    int t = threadIdx.x;
    float mu = sums[t] / n;
    float var = sumsq[t] / n - mu * mu;
    float rs = rsqrtf(var + EPSV);
    float a = rs * gamma1[t];
    a1[t] = a;
    c1[t] = beta1[t] - mu * a;
}

// ------- W1bt[nIdx][k] = bf16(a1[k]*W1[k][nIdx]) ; b1p[nIdx] = c1@W1[:,nIdx] + b1 -------
__global__ __launch_bounds__(256) void convw1_kernel(
    const float* __restrict__ W1, const float* __restrict__ a1,
    const float* __restrict__ c1, const float* __restrict__ b1,
    u16* __restrict__ W1bt, float* __restrict__ b1p)
{
    __shared__ float red[256];
    int nIdx = blockIdx.x;
    int k = threadIdx.x;
    float w = W1[(size_t)k * N_H + nIdx];
    W1bt[(size_t)nIdx * 256 + k] = f2bf(a1[k] * w);
    red[k] = c1[k] * w;
    __syncthreads();
    for (int s = 128; s > 0; s >>= 1) {
        if (k < s) red[k] += red[k + s];
        __syncthreads();
    }
    if (k == 0) b1p[nIdx] = red[0] + b1[nIdx];
}

// ------------- W2bt[nIdx][k] = bf16(W2[k][nIdx]) -------------
__global__ __launch_bounds__(256) void convw2_kernel(
    const float* __restrict__ W2, u16* __restrict__ W2bt)
{
    int nIdx = blockIdx.x;
    int k = threadIdx.x;
    W2bt[(size_t)nIdx * 256 + k] = f2bf(W2[(size_t)k * N_D + nIdx]);
}

// ------------- BN2 per-column affine -------------
__global__ __launch_bounds__(256) void prep2_kernel(
    const float* __restrict__ sums2, const float* __restrict__ sumsq2,
    const float* __restrict__ gamma2, const float* __restrict__ beta2,
    float* __restrict__ a2, float* __restrict__ c2, float n)
{
    int t = threadIdx.x;
    float mu = sums2[t] / n;
    float var = sumsq2[t] / n - mu * mu;
    float rs = rsqrtf(var + EPSV);
    float a = rs * gamma2[t];
    a2[t] = a;
    c2[t] = beta2[t] - mu * a;
}

// ------------- GEMM1 (MFMA): ybf = bf16(xbf @ W1bt^T + b1p), + column stats -------------
__global__ __launch_bounds__(256) void gemm1_kernel(
    const u16* __restrict__ xbf, const u16* __restrict__ W1bt,
    const float* __restrict__ b1p, u16* __restrict__ ybf,
    float* __restrict__ sums2, float* __restrict__ sumsq2, int n)
{
    __shared__ __align__(16) u16 As[128 * 32];
    __shared__ __align__(16) u16 Bs[128 * 32];
    __shared__ float ssum[128];
    __shared__ float ssq[128];
    int t = threadIdx.x;
    int w = t >> 6, l = t & 63;
    int row0 = blockIdx.x * 128;
    int col0 = blockIdx.y * 128;
    int wrow = (w & 1) * 64, wcol = (w >> 1) * 64;
    int lm = l & 15, lq = l >> 4;
    if (t < 128) { ssum[t] = 0.f; ssq[t] = 0.f; }

    floatx4 acc[4][4];
#pragma unroll
    for (int i = 0; i < 4; ++i)
#pragma unroll
        for (int j = 0; j < 4; ++j) acc[i][j] = (floatx4){0.f, 0.f, 0.f, 0.f};

    for (int k0 = 0; k0 < N_H; k0 += 32) {
#pragma unroll
        for (int i = 0; i < 2; ++i) {
            int rowl = i * 64 + w * 16 + (l >> 2);
            int gcol = k0 + (l & 3) * 8;
            load16_to_lds(&xbf[(size_t)(row0 + rowl) * 256 + gcol],
                          &As[(i * 64 + w * 16) * 32]);
            load16_to_lds(&W1bt[(size_t)(col0 + rowl) * 256 + gcol],
                          &Bs[(i * 64 + w * 16) * 32]);
        }
        __syncthreads();
        short8 a[4], b[4];
#pragma unroll
        for (int f = 0; f < 4; ++f) {
            a[f] = *(const short8*)&As[(wrow + f * 16 + lm) * 32 + lq * 8];
            b[f] = *(const short8*)&Bs[(wcol + f * 16 + lm) * 32 + lq * 8];
        }
#pragma unroll
        for (int fm = 0; fm < 4; ++fm)
#pragma unroll
            for (int fn = 0; fn < 4; ++fn)
                acc[fm][fn] = __builtin_amdgcn_mfma_f32_16x16x32_bf16(
                    a[fm], b[fn], acc[fm][fn], 0, 0, 0);
        __syncthreads();
    }

    float cs[4] = {0.f, 0.f, 0.f, 0.f};
    float cq[4] = {0.f, 0.f, 0.f, 0.f};
#pragma unroll
    for (int fn = 0; fn < 4; ++fn) {
        int c = col0 + wcol + fn * 16 + lm;
        float bb = b1p[c];
#pragma unroll
        for (int fm = 0; fm < 4; ++fm) {
            int rbase = row0 + wrow + fm * 16 + lq * 4;
#pragma unroll
            for (int i = 0; i < 4; ++i) {
                int r = rbase + i;
                if (r < n) {
                    float v = acc[fm][fn][i] + bb;
                    ybf[(size_t)r * 256 + c] = f2bf(v);
                    cs[fn] += v; cq[fn] += v * v;
                }
            }
        }
    }
#pragma unroll
    for (int fn = 0; fn < 4; ++fn) {
        atomicAdd(&ssum[wcol + fn * 16 + lm], cs[fn]);
        atomicAdd(&ssq[wcol + fn * 16 + lm], cq[fn]);
    }
    __syncthreads();
    if (t < 128) {
        atomicAdd(&sums2[col0 + t], ssum[t]);
        atomicAdd(&sumsq2[col0 + t], ssq[t]);
    }
}

// ------------- GEMM2 (MFMA): out = relu(a2*ybf + c2) @ W2bt^T + b2 (fp32 out) -------------
__global__ __launch_bounds__(256) void gemm2_kernel(
    const u16* __restrict__ ybf, const u16* __restrict__ W2bt,
    const float* __restrict__ a2, const float* __restrict__ c2,
    const float* __restrict__ b2, float* __restrict__ out, int n)
{
    __shared__ __align__(16) u16 As[128 * 32];
    __shared__ __align__(16) u16 Bs[128 * 32];
    int t = threadIdx.x;
    int w = t >> 6, l = t & 63;
    int row0 = blockIdx.x * 128;
    int wrow = (w & 1) * 64, wcol = (w >> 1) * 64;
    int lm = l & 15, lq = l >> 4;

    floatx4 acc[4][4];
#pragma unroll
    for (int i = 0; i < 4; ++i)
#pragma unroll
        for (int j = 0; j < 4; ++j) acc[i][j] = (floatx4){0.f, 0.f, 0.f, 0.f};

    for (int k0 = 0; k0 < N_H; k0 += 32) {
#pragma unroll
        for (int i = 0; i < 2; ++i) {
            int rowl = i * 64 + w * 16 + (l >> 2);
            int gcol = k0 + (l & 3) * 8;
            load16_to_lds(&W2bt[(size_t)rowl * 256 + gcol],
                          &Bs[(i * 64 + w * 16) * 32]);
        }
        int kc = k0 + (t & 3) * 8;
        float4 aa0 = *(const float4*)&a2[kc];
        float4 aa1 = *(const float4*)&a2[kc + 4];
        float4 cc0 = *(const float4*)&c2[kc];
        float4 cc1 = *(const float4*)&c2[kc + 4];
#pragma unroll
        for (int i = 0; i < 2; ++i) {
            int rowl = i * 64 + (t >> 2);
            uint4 raw = *(const uint4*)&ybf[(size_t)(row0 + rowl) * 256 + kc];
            float z0 = fmaxf(bf2f(raw.x & 0xFFFF) * aa0.x + cc0.x, 0.f);
            float z1 = fmaxf(bf2f(raw.x >> 16)    * aa0.y + cc0.y, 0.f);
            float z2 = fmaxf(bf2f(raw.y & 0xFFFF) * aa0.z + cc0.z, 0.f);
            float z3 = fmaxf(bf2f(raw.y >> 16)    * aa0.w + cc0.w, 0.f);
            float z4 = fmaxf(bf2f(raw.z & 0xFFFF) * aa1.x + cc1.x, 0.f);
            float z5 = fmaxf(bf2f(raw.z >> 16)    * aa1.y + cc1.y, 0.f);
            float z6 = fmaxf(bf2f(raw.w & 0xFFFF) * aa1.z + cc1.z, 0.f);
            float z7 = fmaxf(bf2f(raw.w >> 16)    * aa1.w + cc1.w, 0.f);
            uint4 pk;
            pk.x = f2bf(z0) | ((unsigned)f2bf(z1) << 16);
            pk.y = f2bf(z2) | ((unsigned)f2bf(z3) << 16);
            pk.z = f2bf(z4) | ((unsigned)f2bf(z5) << 16);
            pk.w = f2bf(z6) | ((unsigned)f2bf(z7) << 16);
            *(uint4*)&As[rowl * 32 + (t & 3) * 8] = pk;
        }
        __syncthreads();
        short8 a[4], b[4];
#pragma unroll
        for (int f = 0; f < 4; ++f) {
            a[f] = *(const short8*)&As[(wrow + f * 16 + lm) * 32 + lq * 8];
            b[f] = *(const short8*)&Bs[(wcol + f * 16 + lm) * 32 + lq * 8];
        }
#pragma unroll
        for (int fm = 0; fm < 4; ++fm)
#pragma unroll
            for (int fn = 0; fn < 4; ++fn)
                acc[fm][fn] = __builtin_amdgcn_mfma_f32_16x16x32_bf16(
                    a[fm], b[fn], acc[fm][fn], 0, 0, 0);
        __syncthreads();
    }

#pragma unroll
    for (int fn = 0; fn < 4; ++fn) {
        int c = wcol + fn * 16 + lm;
        float bb = b2[c];
#pragma unroll
        for (int fm = 0; fm < 4; ++fm) {
            int rbase = row0 + wrow + fm * 16 + lq * 4;
#pragma unroll
            for (int i = 0; i < 4; ++i) {
                int r = rbase + i;
                if (r < n) out[(size_t)r * N_D + c] = acc[fm][fn][i] + bb;
            }
        }
    }
}

extern "C" void kernel_launch(void* const* d_in, const int* in_sizes, int n_in,
                              void* d_out, int out_size, void* d_ws, size_t ws_size,
                              hipStream_t stream)
{
    const float* input    = (const float*)d_in[0];
    const int*   adj_rows = (const int*)d_in[1];
    const int*   adj_cols = (const int*)d_in[2];
    const float* adj_vals = (const float*)d_in[3];
    const float* gamma1   = (const float*)d_in[4];
    const float* beta1    = (const float*)d_in[5];
    const float* W1       = (const float*)d_in[6];
    const float* b1       = (const float*)d_in[7];
    const float* gamma2   = (const float*)d_in[8];
    const float* beta2    = (const float*)d_in[9];
    const float* W2       = (const float*)d_in[10];
    const float* b2       = (const float*)d_in[11];

    int n = in_sizes[0] / N_D;   // 100000
    int E = in_sizes[1];         // 1600000
    size_t n_pad = ((size_t)n + 127) & ~(size_t)127;

    u16* xbf = (u16*)d_ws;                         // n_pad*256 bf16
    u16* ybf = xbf + n_pad * 256;                  // n_pad*256 bf16
    int2* edges = (int2*)ybf;                      // E int2 (aliases ybf; consumed pre-gemm1)
    u16* W1bt = ybf + n_pad * 256;                 // 256*256 bf16
    u16* W2bt = W1bt + 256 * 256;                  // 128*256 bf16
    float* stats  = (float*)(W2bt + 128 * 256);
    float* sums1  = stats;
    float* sumsq1 = stats + 256;
    float* a1     = stats + 512;
    float* b1p    = stats + 768;
    float* sums2  = stats + 1024;
    float* sumsq2 = stats + 1280;
    float* a2     = stats + 1536;
    float* c2     = stats + 1792;
    float* c1     = stats + 2048;
    int* cnt       = (int*)(stats + 2304);
    int* rowPtr    = cnt + n;
    int* blockSums = rowPtr + n;

    hipMemsetAsync(cnt, 0, (size_t)n * sizeof(int), stream);
    hipMemsetAsync(stats, 0, 2048 * sizeof(float), stream);

    convin_count_kernel<<<(n * 32 + 255) / 256, 256, 0, stream>>>(
        input, xbf, adj_rows, cnt, n, E);
    convw2_kernel<<<128, 256, 0, stream>>>(W2, W2bt);

    int nb = (n + SCAN_B - 1) / SCAN_B;
    scanA_kernel<<<nb, SCAN_B, 0, stream>>>(cnt, rowPtr, blockSums, n);
    scanB_kernel<<<1, 128, 0, stream>>>(blockSums, nb);
    scanC_kernel<<<nb, SCAN_B, 0, stream>>>(rowPtr, blockSums, n);

    // XCD-colored scatter: 8 colors x 256 segments
    scatter_kernel<<<2048, 256, 0, stream>>>(adj_rows, adj_cols, adj_vals, rowPtr, edges, E);

    aggregate_kernel<<<(n + 3) / 4, 256, 0, stream>>>(
        (const unsigned*)xbf, rowPtr, cnt, edges, (unsigned*)xbf, n);

    xstats_kernel<<<(n + STAT_ROWS - 1) / STAT_ROWS, 256, 0, stream>>>(xbf, sums1, sumsq1, n);

    prep1a_kernel<<<1, 256, 0, stream>>>(sums1, sumsq1, gamma1, beta1, a1, c1, (float)n);
    convw1_kernel<<<256, 256, 0, stream>>>(W1, a1, c1, b1, W1bt, b1p);

    dim3 g1((unsigned)(n_pad / 128), 2);
    gemm1_kernel<<<g1, 256, 0, stream>>>(xbf, W1bt, b1p, ybf, sums2, sumsq2, n);

    prep2_kernel<<<1, 256, 0, stream>>>(sums2, sumsq2, gamma2, beta2, a2, c2, (float)n);

    gemm2_kernel<<<(unsigned)(n_pad / 128), 256, 0, stream>>>(ybf, W2bt, a2, c2, b2, (float*)d_out, n);
}